// Round 1
// baseline (294.621 us; speedup 1.0000x reference)
//
#include <hip/hip_runtime.h>

#define L_SEQ 8192
#define N_FFT 16384
#define HID 256

__device__ __forceinline__ float2 cmul(float2 a, float2 b) {
  return make_float2(a.x*b.x - a.y*b.y, a.x*b.y + a.y*b.x);
}
__device__ __forceinline__ float2 cadd(float2 a, float2 b){ return make_float2(a.x+b.x, a.y+b.y); }
__device__ __forceinline__ float2 csub(float2 a, float2 b){ return make_float2(a.x-b.x, a.y-b.y); }

// Forward DIF radix-4, N=16384: natural input -> digit-reversed output, in place.
// Genuine DFT up to a fixed output permutation (same permutation for kernel and
// signal spectra, so pointwise multiply in the permuted domain == conv).
__device__ void fft_fwd(float2* X, int tid) {
  for (int m = N_FFT/4; m >= 1; m >>= 2) {
    __syncthreads();
    const float ang = -6.2831853071795864769f / (float)(4*m);
    for (int j = tid; j < N_FFT/4; j += 256) {
      int i = j & (m-1);
      int base = ((j - i) << 2) + i;   // (j/m)*4m + i
      float2 a0 = X[base], a1 = X[base+m], a2 = X[base+2*m], a3 = X[base+3*m];
      float2 t0 = cadd(a0,a2), t1 = csub(a0,a2), t2 = cadd(a1,a3), t3 = csub(a1,a3);
      float2 b0 = cadd(t0,t2);
      float2 b2 = csub(t0,t2);
      float2 b1 = make_float2(t1.x + t3.y, t1.y - t3.x);  // t1 - i*t3
      float2 b3 = make_float2(t1.x - t3.y, t1.y + t3.x);  // t1 + i*t3
      float s, c;
      __sincosf(ang * (float)i, &s, &c);
      float2 w1 = make_float2(c, s);
      float2 w2 = cmul(w1, w1);
      float2 w3 = cmul(w2, w1);
      X[base]     = b0;
      X[base+m]   = cmul(b1, w1);
      X[base+2*m] = cmul(b2, w2);
      X[base+3*m] = cmul(b3, w3);
    }
  }
}

// Exact algebraic inverse of fft_fwd (unscaled: returns N*x). Digit-reversed
// input -> natural output, in place.
__device__ void fft_inv(float2* X, int tid) {
  for (int m = 1; m <= N_FFT/4; m <<= 2) {
    __syncthreads();
    const float ang = 6.2831853071795864769f / (float)(4*m);
    for (int j = tid; j < N_FFT/4; j += 256) {
      int i = j & (m-1);
      int base = ((j - i) << 2) + i;
      float s, c;
      __sincosf(ang * (float)i, &s, &c);
      float2 w1 = make_float2(c, s);
      float2 w2 = cmul(w1, w1);
      float2 w3 = cmul(w2, w1);
      float2 c0 = X[base];
      float2 c1 = cmul(X[base+m],   w1);
      float2 c2 = cmul(X[base+2*m], w2);
      float2 c3 = cmul(X[base+3*m], w3);
      float2 u0 = cadd(c0,c2), u2 = csub(c0,c2);
      float2 u1 = cadd(c1,c3);
      float2 v3 = make_float2(c3.y - c1.y, c1.x - c3.x);  // i*(c1-c3)
      X[base]     = cadd(u0,u1);
      X[base+2*m] = csub(u0,u1);
      X[base+m]   = cadd(u2,v3);
      X[base+3*m] = csub(u2,v3);
    }
  }
}

// Filter generation: MLP over positional embedding, exp-decay window, D folded
// into tap 0. Grid (32 l-blocks, 8 c-chunks) x 256 threads; one l per thread,
// 32 channels per block (redundant MLP per c-chunk, ~2x total cost, keeps all
// 256 CUs busy).
__global__ __launch_bounds__(256) void kgen_kernel(
    const float* __restrict__ W1, const float* __restrict__ b1, const float* __restrict__ fq0,
    const float* __restrict__ W2, const float* __restrict__ b2, const float* __restrict__ fq1,
    const float* __restrict__ W3, const float* __restrict__ b3, const float* __restrict__ fq2,
    const float* __restrict__ Wout, const float* __restrict__ Dv, float* __restrict__ kbuf) {
  int l = blockIdx.x * 256 + threadIdx.x;
  int c0 = blockIdx.y * 32;
  float t = (float)l * (1.0f / (float)(L_SEQ - 1));
  float w = 6.2831853071795864769f * (float)l / (float)L_SEQ;
  float z0 = t;
  float z1 = __cosf(1e-4f * w);
  float z2 = __cosf(w);
  float z3 = -__sinf(1e-4f * w);
  float z4 = -__sinf(w);
  float ha[64];
  #pragma unroll
  for (int o = 0; o < 64; ++o) {
    float acc = b1[o] + z0*W1[o*5+0] + z1*W1[o*5+1] + z2*W1[o*5+2]
                      + z3*W1[o*5+3] + z4*W1[o*5+4];
    ha[o] = __sinf(fq0[o] * acc);
  }
  float hb[64];
  #pragma unroll
  for (int p = 0; p < 64; ++p) {
    float acc = b2[p];
    #pragma unroll
    for (int o = 0; o < 64; ++o) acc += ha[o] * W2[p*64+o];
    hb[p] = __sinf(fq1[p] * acc);
  }
  #pragma unroll
  for (int p = 0; p < 64; ++p) {
    float acc = b3[p];
    #pragma unroll
    for (int o = 0; o < 64; ++o) acc += hb[o] * W3[p*64+o];
    ha[p] = __sinf(fq2[p] * acc);   // ha now holds h3
  }
  const float mind = -3.0701134573253945f;    // ln(0.01)/1.5
  const float maxd = -15.350567286626972f;    // ln(0.01)/0.3
  for (int jj = 0; jj < 32; ++jj) {
    int c = c0 + jj;
    float acc = 0.f;
    #pragma unroll
    for (int o = 0; o < 64; ++o) acc += ha[o] * Wout[c*64+o];
    float delta = mind + (maxd - mind) * ((float)c * (1.0f/255.0f));
    float dec = __expf(-t * fabsf(delta)) + 0.05f;
    float v = acc * dec;
    if (l == 0) v += Dv[c];                   // conv(u, k + D*delta) = conv + D*u
    kbuf[(size_t)c * L_SEQ + l] = v;
  }
}

// Per-channel kernel spectrum (digit-reversed domain), scaled by 1/N.
__global__ __launch_bounds__(256) void kf_kernel(const float* __restrict__ kbuf,
                                                 float2* __restrict__ Kf) {
  __shared__ float2 X[N_FFT];   // 128 KB
  int c = blockIdx.x;
  int tid = threadIdx.x;
  const float* kr = kbuf + (size_t)c * L_SEQ;
  for (int q = 0; q < L_SEQ/256; ++q) {
    int idx = tid + 256*q;
    X[idx] = make_float2(kr[idx], 0.f);
    X[idx + L_SEQ] = make_float2(0.f, 0.f);
  }
  fft_fwd(X, tid);
  __syncthreads();
  float2* out = Kf + (size_t)c * N_FFT;
  const float sc = 1.0f / (float)N_FFT;
  for (int q = 0; q < N_FFT/256; ++q) {
    int idx = tid + 256*q;
    float2 v = X[idx];
    out[idx] = make_float2(v.x*sc, v.y*sc);
  }
}

// Conv: pack two batches (p, p+4) of one channel as one complex sequence
// (kernel is real => conv distributes over Re/Im), FFT, pointwise, inverse.
__global__ __launch_bounds__(256) void conv_kernel(const float* __restrict__ x,
                                                   const float2* __restrict__ Kf,
                                                   float* __restrict__ y) {
  __shared__ float2 X[N_FFT];   // 128 KB
  int c = blockIdx.x;           // 256 channels
  int p = blockIdx.y;           // 4 batch pairs
  int tid = threadIdx.x;
  const float* u0 = x + ((size_t)p       * HID + c) * L_SEQ;
  const float* u1 = x + ((size_t)(p + 4) * HID + c) * L_SEQ;
  for (int q = 0; q < 32; ++q) {
    int idx = tid + 256*q;
    X[idx] = make_float2(u0[idx], u1[idx]);
    X[idx + L_SEQ] = make_float2(0.f, 0.f);
  }
  fft_fwd(X, tid);
  __syncthreads();
  const float2* kf = Kf + (size_t)c * N_FFT;
  for (int q = 0; q < 64; ++q) {
    int idx = tid + 256*q;
    X[idx] = cmul(X[idx], kf[idx]);
  }
  fft_inv(X, tid);
  __syncthreads();
  float* y0 = y + ((size_t)p       * HID + c) * L_SEQ;
  float* y1 = y + ((size_t)(p + 4) * HID + c) * L_SEQ;
  for (int q = 0; q < 32; ++q) {
    int idx = tid + 256*q;
    float2 v = X[idx];
    y0[idx] = v.x;
    y1[idx] = v.y;
  }
}

extern "C" void kernel_launch(void* const* d_in, const int* in_sizes, int n_in,
                              void* d_out, int out_size, void* d_ws, size_t ws_size,
                              hipStream_t stream) {
  const float* x    = (const float*)d_in[0];
  const float* W1   = (const float*)d_in[1];
  const float* b1   = (const float*)d_in[2];
  const float* fq0  = (const float*)d_in[3];
  const float* W2   = (const float*)d_in[4];
  const float* b2   = (const float*)d_in[5];
  const float* fq1  = (const float*)d_in[6];
  const float* W3   = (const float*)d_in[7];
  const float* b3   = (const float*)d_in[8];
  const float* fq2  = (const float*)d_in[9];
  const float* Wout = (const float*)d_in[10];
  const float* Dv   = (const float*)d_in[11];

  float*  kbuf = (float*)d_ws;                                          // 8 MB
  float2* Kf   = (float2*)((char*)d_ws + (size_t)HID * L_SEQ * sizeof(float)); // +32 MB
  float*  y    = (float*)d_out;

  kgen_kernel<<<dim3(32, 8), 256, 0, stream>>>(W1,b1,fq0,W2,b2,fq1,W3,b3,fq2,Wout,Dv,kbuf);
  kf_kernel  <<<dim3(256),   256, 0, stream>>>(kbuf, Kf);
  conv_kernel<<<dim3(256,4), 256, 0, stream>>>(x, Kf, y);
}

// Round 2
// 219.153 us; speedup vs baseline: 1.3444x; 1.3444x over previous
//
#include <hip/hip_runtime.h>

#define L_SEQ 8192
#define N_FFT 16384
#define NTH 512
#define HID 256
#define PIDX(i) ((i) + ((i) >> 5))
#define LDS_SZ (N_FFT + (N_FFT >> 5))   // 16896 float2 = 132 KB

__device__ __forceinline__ float2 cmul(float2 a, float2 b) {
  return make_float2(a.x*b.x - a.y*b.y, a.x*b.y + a.y*b.x);
}
__device__ __forceinline__ float2 cadd(float2 a, float2 b){ return make_float2(a.x+b.x, a.y+b.y); }
__device__ __forceinline__ float2 csub(float2 a, float2 b){ return make_float2(a.x-b.x, a.y-b.y); }

// radix-4 DIF forward butterfly (outputs in output-digit order 0..3)
__device__ __forceinline__ void bf4_fwd(float2 a0, float2 a1, float2 a2, float2 a3,
                                        float2& o0, float2& o1, float2& o2, float2& o3) {
  float2 t0 = cadd(a0,a2), t1 = csub(a0,a2), t2 = cadd(a1,a3), t3 = csub(a1,a3);
  o0 = cadd(t0,t2);
  o2 = csub(t0,t2);
  o1 = make_float2(t1.x + t3.y, t1.y - t3.x);   // t1 - i*t3
  o3 = make_float2(t1.x - t3.y, t1.y + t3.x);   // t1 + i*t3
}
// radix-4 DIT inverse butterfly
__device__ __forceinline__ void bf4_inv(float2 c0, float2 c1, float2 c2, float2 c3,
                                        float2& o0, float2& o1, float2& o2, float2& o3) {
  float2 u0 = cadd(c0,c2), u2 = csub(c0,c2), u1 = cadd(c1,c3);
  float2 v3 = make_float2(c3.y - c1.y, c1.x - c3.x);  // i*(c1-c3)
  o0 = cadd(u0,u1); o2 = csub(u0,u1); o1 = cadd(u2,v3); o3 = csub(u2,v3);
}

// omega16^a = exp(-2*pi*i*a/16), a = 0..3
__device__ __constant__ const float W16C[4] = {1.0f, 0.92387953251128674f, 0.70710678118654752f, 0.38268343236508977f};
__device__ __constant__ const float W16S[4] = {0.0f, -0.38268343236508977f, -0.70710678118654752f, -0.92387953251128674f};

// Fused pair of forward DIF radix-4 stages (m = MB, then m = MB/4) in registers.
// Identical math to two successive stages of the reference radix-4 loop.
template<int MB>
__device__ void fwd_pair(float2* __restrict__ X, int tid) {
  const int MQ = MB / 4;
  #pragma unroll
  for (int r = 0; r < N_FFT/16/NTH; ++r) {
    int s = tid + r*NTH;
    int g = s / MQ;
    int i2 = s & (MQ-1);
    int base = g*4*MB + i2;
    float2 e[4][4];
    #pragma unroll
    for (int a = 0; a < 4; ++a)
      #pragma unroll
      for (int b = 0; b < 4; ++b)
        e[a][b] = X[PIDX(base + a*MQ + b*MB)];
    float sb, cb;
    __sincosf(-6.2831853071795864769f * (float)i2 / (float)(4*MB), &sb, &cb);
    float2 wb = make_float2(cb, sb);          // exp(-2pi*i2/(4*MB))
    // stage MB: butterfly over b for each a; twiddle w(a) = wb * omega16^a
    float2 f[4][4];
    #pragma unroll
    for (int a = 0; a < 4; ++a) {
      float2 wa = cmul(wb, make_float2(W16C[a], W16S[a]));
      float2 w2 = cmul(wa, wa), w3 = cmul(w2, wa);
      float2 o0,o1,o2,o3;
      bf4_fwd(e[a][0], e[a][1], e[a][2], e[a][3], o0,o1,o2,o3);
      f[a][0] = o0; f[a][1] = cmul(o1,wa); f[a][2] = cmul(o2,w2); f[a][3] = cmul(o3,w3);
    }
    // stage MQ: butterfly over a for each b; twiddle w' = wb^4 (indep of a,b)
    float2 wp = cmul(wb,wb); wp = cmul(wp,wp);
    float2 wp2 = cmul(wp,wp), wp3 = cmul(wp2,wp);
    #pragma unroll
    for (int b = 0; b < 4; ++b) {
      float2 o0,o1,o2,o3;
      bf4_fwd(f[0][b], f[1][b], f[2][b], f[3][b], o0,o1,o2,o3);
      X[PIDX(base + 0*MQ + b*MB)] = o0;
      X[PIDX(base + 1*MQ + b*MB)] = cmul(o1,wp);
      X[PIDX(base + 2*MQ + b*MB)] = cmul(o2,wp2);
      X[PIDX(base + 3*MQ + b*MB)] = cmul(o3,wp3);
    }
  }
}

// Fused pair of inverse DIT radix-4 stages (m = MB/4, then m = MB) in registers.
template<int MB>
__device__ void inv_pair(float2* __restrict__ X, int tid) {
  const int MQ = MB / 4;
  #pragma unroll
  for (int r = 0; r < N_FFT/16/NTH; ++r) {
    int s = tid + r*NTH;
    int g = s / MQ;
    int i2 = s & (MQ-1);
    int base = g*4*MB + i2;
    float2 e[4][4];
    #pragma unroll
    for (int a = 0; a < 4; ++a)
      #pragma unroll
      for (int b = 0; b < 4; ++b)
        e[a][b] = X[PIDX(base + a*MQ + b*MB)];
    float sb, cb;
    __sincosf(6.2831853071795864769f * (float)i2 / (float)(4*MB), &sb, &cb);
    float2 wb = make_float2(cb, sb);          // exp(+2pi*i2/(4*MB))
    // stage MQ: twiddle w = wb^4 on inputs, butterfly over a for each b
    float2 wq = cmul(wb,wb); wq = cmul(wq,wq);
    float2 wq2 = cmul(wq,wq), wq3 = cmul(wq2,wq);
    float2 f[4][4];
    #pragma unroll
    for (int b = 0; b < 4; ++b) {
      float2 c0 = e[0][b];
      float2 c1 = cmul(e[1][b], wq);
      float2 c2 = cmul(e[2][b], wq2);
      float2 c3 = cmul(e[3][b], wq3);
      float2 o0,o1,o2,o3;
      bf4_inv(c0,c1,c2,c3, o0,o1,o2,o3);
      f[0][b]=o0; f[1][b]=o1; f[2][b]=o2; f[3][b]=o3;
    }
    // stage MB: twiddle per a: W(a) = wb * conj(omega16^a), butterfly over b
    #pragma unroll
    for (int a = 0; a < 4; ++a) {
      float2 W1 = cmul(wb, make_float2(W16C[a], -W16S[a]));
      float2 W2 = cmul(W1,W1), W3 = cmul(W2,W1);
      float2 c0 = f[a][0];
      float2 c1 = cmul(f[a][1], W1);
      float2 c2 = cmul(f[a][2], W2);
      float2 c3 = cmul(f[a][3], W3);
      float2 o0,o1,o2,o3;
      bf4_inv(c0,c1,c2,c3, o0,o1,o2,o3);
      X[PIDX(base + a*MQ + 0*MB)] = o0;
      X[PIDX(base + a*MQ + 1*MB)] = o1;
      X[PIDX(base + a*MQ + 2*MB)] = o2;
      X[PIDX(base + a*MQ + 3*MB)] = o3;
    }
  }
}

// ---------------- filter generation (unchanged from R1) ----------------
__global__ __launch_bounds__(256) void kgen_kernel(
    const float* __restrict__ W1, const float* __restrict__ b1, const float* __restrict__ fq0,
    const float* __restrict__ W2, const float* __restrict__ b2, const float* __restrict__ fq1,
    const float* __restrict__ W3, const float* __restrict__ b3, const float* __restrict__ fq2,
    const float* __restrict__ Wout, const float* __restrict__ Dv, float* __restrict__ kbuf) {
  int l = blockIdx.x * 256 + threadIdx.x;
  int c0 = blockIdx.y * 32;
  float t = (float)l * (1.0f / (float)(L_SEQ - 1));
  float w = 6.2831853071795864769f * (float)l / (float)L_SEQ;
  float z0 = t;
  float z1 = __cosf(1e-4f * w);
  float z2 = __cosf(w);
  float z3 = -__sinf(1e-4f * w);
  float z4 = -__sinf(w);
  float ha[64];
  #pragma unroll
  for (int o = 0; o < 64; ++o) {
    float acc = b1[o] + z0*W1[o*5+0] + z1*W1[o*5+1] + z2*W1[o*5+2]
                      + z3*W1[o*5+3] + z4*W1[o*5+4];
    ha[o] = __sinf(fq0[o] * acc);
  }
  float hb[64];
  #pragma unroll
  for (int p = 0; p < 64; ++p) {
    float acc = b2[p];
    #pragma unroll
    for (int o = 0; o < 64; ++o) acc += ha[o] * W2[p*64+o];
    hb[p] = __sinf(fq1[p] * acc);
  }
  #pragma unroll
  for (int p = 0; p < 64; ++p) {
    float acc = b3[p];
    #pragma unroll
    for (int o = 0; o < 64; ++o) acc += hb[o] * W3[p*64+o];
    ha[p] = __sinf(fq2[p] * acc);   // ha now holds h3
  }
  const float mind = -3.0701134573253945f;    // ln(0.01)/1.5
  const float maxd = -15.350567286626972f;    // ln(0.01)/0.3
  for (int jj = 0; jj < 32; ++jj) {
    int c = c0 + jj;
    float acc = 0.f;
    #pragma unroll
    for (int o = 0; o < 64; ++o) acc += ha[o] * Wout[c*64+o];
    float delta = mind + (maxd - mind) * ((float)c * (1.0f/255.0f));
    float dec = __expf(-t * fabsf(delta)) + 0.05f;
    float v = acc * dec;
    if (l == 0) v += Dv[c];                   // conv(u, k + D*delta) = conv + D*u
    kbuf[(size_t)c * L_SEQ + l] = v;
  }
}

// ---------------- kernel spectrum ----------------
__global__ __launch_bounds__(NTH) void kf_kernel(const float* __restrict__ kbuf,
                                                 float2* __restrict__ Kf) {
  __shared__ float2 X[LDS_SZ];
  int c = blockIdx.x;
  int tid = threadIdx.x;
  const float4* kr4 = (const float4*)(kbuf + (size_t)c * L_SEQ);
  #pragma unroll
  for (int q = 0; q < L_SEQ/4/NTH; ++q) {     // 4 iters
    int t4 = tid + q*NTH;
    float4 v = kr4[t4];
    int base = 4*t4;
    X[PIDX(base+0)] = make_float2(v.x, 0.f);
    X[PIDX(base+1)] = make_float2(v.y, 0.f);
    X[PIDX(base+2)] = make_float2(v.z, 0.f);
    X[PIDX(base+3)] = make_float2(v.w, 0.f);
  }
  #pragma unroll
  for (int q = 0; q < L_SEQ/NTH; ++q) {       // 16 iters
    int idx = L_SEQ + tid + q*NTH;
    X[PIDX(idx)] = make_float2(0.f, 0.f);
  }
  __syncthreads();
  fwd_pair<4096>(X, tid); __syncthreads();
  fwd_pair<256>(X, tid);  __syncthreads();
  fwd_pair<16>(X, tid);   __syncthreads();
  // last fwd stage (m=1, twiddle=1) fused with scaled store, digit-reversed layout
  float2* out = Kf + (size_t)c * N_FFT;
  const float sc = 1.0f / (float)N_FFT;
  #pragma unroll
  for (int r = 0; r < N_FFT/4/NTH; ++r) {     // 8 iters
    int j = tid + r*NTH;
    int base = 4*j;
    float2 o0,o1,o2,o3;
    bf4_fwd(X[PIDX(base)], X[PIDX(base+1)], X[PIDX(base+2)], X[PIDX(base+3)], o0,o1,o2,o3);
    out[base+0] = make_float2(o0.x*sc, o0.y*sc);
    out[base+1] = make_float2(o1.x*sc, o1.y*sc);
    out[base+2] = make_float2(o2.x*sc, o2.y*sc);
    out[base+3] = make_float2(o3.x*sc, o3.y*sc);
  }
}

// ---------------- conv: pack 2 batches as complex, FFT, pointwise, IFFT ----------------
__global__ __launch_bounds__(NTH) void conv_kernel(const float* __restrict__ x,
                                                   const float2* __restrict__ Kf,
                                                   float* __restrict__ y) {
  __shared__ float2 X[LDS_SZ];
  int c = blockIdx.x;
  int p = blockIdx.y;
  int tid = threadIdx.x;
  const float4* u0 = (const float4*)(x + ((size_t)p       * HID + c) * L_SEQ);
  const float4* u1 = (const float4*)(x + ((size_t)(p + 4) * HID + c) * L_SEQ);
  #pragma unroll
  for (int q = 0; q < L_SEQ/4/NTH; ++q) {     // 4 iters
    int t4 = tid + q*NTH;
    float4 v0 = u0[t4];
    float4 v1 = u1[t4];
    int base = 4*t4;
    X[PIDX(base+0)] = make_float2(v0.x, v1.x);
    X[PIDX(base+1)] = make_float2(v0.y, v1.y);
    X[PIDX(base+2)] = make_float2(v0.z, v1.z);
    X[PIDX(base+3)] = make_float2(v0.w, v1.w);
  }
  #pragma unroll
  for (int q = 0; q < L_SEQ/NTH; ++q) {       // 16 iters
    int idx = L_SEQ + tid + q*NTH;
    X[PIDX(idx)] = make_float2(0.f, 0.f);
  }
  __syncthreads();
  fwd_pair<4096>(X, tid); __syncthreads();
  fwd_pair<256>(X, tid);  __syncthreads();
  fwd_pair<16>(X, tid);   __syncthreads();
  // fused: fwd m=1 (w=1) -> pointwise * Kf -> inv m=1 (w=1)
  {
    const float2* kf = Kf + (size_t)c * N_FFT;
    #pragma unroll
    for (int r = 0; r < N_FFT/4/NTH; ++r) {   // 8 iters
      int j = tid + r*NTH;
      int base = 4*j;
      float2 o0,o1,o2,o3;
      bf4_fwd(X[PIDX(base)], X[PIDX(base+1)], X[PIDX(base+2)], X[PIDX(base+3)], o0,o1,o2,o3);
      float2 k0 = kf[base+0], k1 = kf[base+1], k2 = kf[base+2], k3 = kf[base+3];
      float2 c0 = cmul(o0,k0), c1 = cmul(o1,k1), c2 = cmul(o2,k2), c3 = cmul(o3,k3);
      float2 r0,r1,r2,r3;
      bf4_inv(c0,c1,c2,c3, r0,r1,r2,r3);
      X[PIDX(base+0)] = r0;
      X[PIDX(base+1)] = r1;
      X[PIDX(base+2)] = r2;
      X[PIDX(base+3)] = r3;
    }
  }
  __syncthreads();
  inv_pair<16>(X, tid);   __syncthreads();
  inv_pair<256>(X, tid);  __syncthreads();
  inv_pair<4096>(X, tid); __syncthreads();
  float4* y0 = (float4*)(y + ((size_t)p       * HID + c) * L_SEQ);
  float4* y1 = (float4*)(y + ((size_t)(p + 4) * HID + c) * L_SEQ);
  #pragma unroll
  for (int q = 0; q < L_SEQ/4/NTH; ++q) {     // 4 iters
    int t4 = tid + q*NTH;
    int base = 4*t4;
    float2 r0 = X[PIDX(base+0)];
    float2 r1 = X[PIDX(base+1)];
    float2 r2 = X[PIDX(base+2)];
    float2 r3 = X[PIDX(base+3)];
    y0[t4] = make_float4(r0.x, r1.x, r2.x, r3.x);
    y1[t4] = make_float4(r0.y, r1.y, r2.y, r3.y);
  }
}

extern "C" void kernel_launch(void* const* d_in, const int* in_sizes, int n_in,
                              void* d_out, int out_size, void* d_ws, size_t ws_size,
                              hipStream_t stream) {
  const float* x    = (const float*)d_in[0];
  const float* W1   = (const float*)d_in[1];
  const float* b1   = (const float*)d_in[2];
  const float* fq0  = (const float*)d_in[3];
  const float* W2   = (const float*)d_in[4];
  const float* b2   = (const float*)d_in[5];
  const float* fq1  = (const float*)d_in[6];
  const float* W3   = (const float*)d_in[7];
  const float* b3   = (const float*)d_in[8];
  const float* fq2  = (const float*)d_in[9];
  const float* Wout = (const float*)d_in[10];
  const float* Dv   = (const float*)d_in[11];

  float*  kbuf = (float*)d_ws;                                                  // 8 MB
  float2* Kf   = (float2*)((char*)d_ws + (size_t)HID * L_SEQ * sizeof(float));  // +32 MB
  float*  y    = (float*)d_out;

  kgen_kernel<<<dim3(32, 8), 256, 0, stream>>>(W1,b1,fq0,W2,b2,fq1,W3,b3,fq2,Wout,Dv,kbuf);
  kf_kernel  <<<dim3(256),   NTH, 0, stream>>>(kbuf, Kf);
  conv_kernel<<<dim3(256,4), NTH, 0, stream>>>(x, Kf, y);
}